// Round 1
// baseline (568.599 us; speedup 1.0000x reference)
//
#include <hip/hip_runtime.h>
#include <hip/hip_bf16.h>
#include <stdint.h>

#define B_  2
#define N_  2048
#define E_  1024
#define H_  16
#define D_  64
#define FF_ 4096
#define M_  (B_ * N_)   // 4096 rows total

typedef __bf16 bf16x8 __attribute__((ext_vector_type(8)));
typedef float  f32x4  __attribute__((ext_vector_type(4)));

__device__ __forceinline__ unsigned short f2bf(float x) {
  union { float f; uint32_t u; } v; v.f = x;
  v.u += 0x7fffu + ((v.u >> 16) & 1u);   // RNE
  return (unsigned short)(v.u >> 16);
}

__device__ __forceinline__ void async16(void* lds, const void* g) {
  __builtin_amdgcn_global_load_lds(
      (const __attribute__((address_space(1))) uint32_t*)g,
      (__attribute__((address_space(3))) uint32_t*)lds, 16, 0, 0);
}

// ---------------------------------------------------------------- transpose+convert
// W [K,N] fp32  ->  Wt [N,K] bf16
__global__ __launch_bounds__(256)
void k_transpose_bf16(const float* __restrict__ W, unsigned short* __restrict__ Wt,
                      int K, int N) {
  __shared__ float tile[64][65];
  const int n0 = blockIdx.x * 64, k0 = blockIdx.y * 64;
  const int t = threadIdx.x;
  const int c = t & 63, r4 = t >> 6;
#pragma unroll
  for (int i = 0; i < 16; ++i) {
    int r = r4 + i * 4;
    tile[r][c] = W[(size_t)(k0 + r) * N + n0 + c];
  }
  __syncthreads();
#pragma unroll
  for (int i = 0; i < 16; ++i) {
    int r = r4 + i * 4;                       // output n-row
    Wt[(size_t)(n0 + r) * K + k0 + c] = f2bf(tile[c][r]);
  }
}

// ---------------------------------------------------------------- input proj + LN
__global__ __launch_bounds__(256)
void k_inproj_ln(const float* __restrict__ x, const float* __restrict__ Win,
                 const float* __restrict__ bin, const float* __restrict__ gamma,
                 const float* __restrict__ beta, float* __restrict__ h,
                 unsigned short* __restrict__ hL) {
  const int m = blockIdx.x, t = threadIdx.x;
  const float x0 = x[m * 2], x1 = x[m * 2 + 1];
  float hv[4], s = 0.f, s2 = 0.f;
#pragma unroll
  for (int i = 0; i < 4; ++i) {
    int c = t + i * 256;
    float v = x0 * Win[c] + x1 * Win[E_ + c] + bin[c];
    hv[i] = v; s += v; s2 += v * v;
  }
#pragma unroll
  for (int off = 1; off < 64; off <<= 1) { s += __shfl_xor(s, off); s2 += __shfl_xor(s2, off); }
  __shared__ float ws1[4], ws2[4];
  const int w = t >> 6, lane = t & 63;
  if (lane == 0) { ws1[w] = s; ws2[w] = s2; }
  __syncthreads();
  s  = ws1[0] + ws1[1] + ws1[2] + ws1[3];
  s2 = ws2[0] + ws2[1] + ws2[2] + ws2[3];
  const float mu = s * (1.f / E_);
  const float var = s2 * (1.f / E_) - mu * mu;
  const float rs = 1.f / sqrtf(var + 1e-5f);
#pragma unroll
  for (int i = 0; i < 4; ++i) {
    int c = t + i * 256;
    h [(size_t)m * E_ + c] = hv[i];
    hL[(size_t)m * E_ + c] = f2bf((hv[i] - mu) * rs * gamma[c] + beta[c]);
  }
}

// ---------------------------------------------------------------- LN (h2 -> bf16)
__global__ __launch_bounds__(256)
void k_ln(const float* __restrict__ h, const float* __restrict__ gamma,
          const float* __restrict__ beta, unsigned short* __restrict__ o) {
  const int m = blockIdx.x, t = threadIdx.x;
  const float4 v4 = *reinterpret_cast<const float4*>(&h[(size_t)m * E_ + t * 4]);
  float s = v4.x + v4.y + v4.z + v4.w;
  float s2 = v4.x * v4.x + v4.y * v4.y + v4.z * v4.z + v4.w * v4.w;
#pragma unroll
  for (int off = 1; off < 64; off <<= 1) { s += __shfl_xor(s, off); s2 += __shfl_xor(s2, off); }
  __shared__ float ws1[4], ws2[4];
  const int w = t >> 6, lane = t & 63;
  if (lane == 0) { ws1[w] = s; ws2[w] = s2; }
  __syncthreads();
  s  = ws1[0] + ws1[1] + ws1[2] + ws1[3];
  s2 = ws2[0] + ws2[1] + ws2[2] + ws2[3];
  const float mu = s * (1.f / E_);
  const float var = s2 * (1.f / E_) - mu * mu;
  const float rs = 1.f / sqrtf(var + 1e-5f);
  const float vv[4] = {v4.x, v4.y, v4.z, v4.w};
#pragma unroll
  for (int i = 0; i < 4; ++i) {
    int c = t * 4 + i;
    o[(size_t)m * E_ + c] = f2bf((vv[i] - mu) * rs * gamma[c] + beta[c]);
  }
}

// ---------------------------------------------------------------- GEMM
// C[M,N] = A[M,K](bf16) * Bt[N,K](bf16)^T + bias (+res) (+gelu)
template <bool OUT_BF16, bool GELU, bool RES>
__global__ __launch_bounds__(256, 2)
void k_gemm(const unsigned short* __restrict__ A, const unsigned short* __restrict__ Bt,
            const float* __restrict__ bias, const float* __restrict__ res,
            void* __restrict__ Cout, int M, int N, int K) {
  __shared__ unsigned short As[128 * 64];
  __shared__ unsigned short Bs[128 * 64];
  const int t = threadIdx.x, lane = t & 63, w = t >> 6;
  const int wr = w >> 1, wc = w & 1;
  const int row0 = blockIdx.y * 128, col0 = blockIdx.x * 128;
  const int lr = lane & 15, lk = (lane >> 4) * 8;

  f32x4 acc[4][4];
#pragma unroll
  for (int m = 0; m < 4; ++m)
#pragma unroll
    for (int n = 0; n < 4; ++n) acc[m][n] = f32x4{0.f, 0.f, 0.f, 0.f};

  for (int k0 = 0; k0 < K; k0 += 64) {
    __syncthreads();
#pragma unroll
    for (int it = 0; it < 4; ++it) {
      int e = (it * 256 + t) * 8;
      int r = e >> 6, c = e & 63;
      async16(&As[(it * 256 + w * 64) * 8], &A [(size_t)(row0 + r) * K + k0 + c]);
      async16(&Bs[(it * 256 + w * 64) * 8], &Bt[(size_t)(col0 + r) * K + k0 + c]);
    }
    __syncthreads();
#pragma unroll
    for (int ks = 0; ks < 2; ++ks) {
      bf16x8 af[4], bfr[4];
#pragma unroll
      for (int m = 0; m < 4; ++m)
        af[m] = *reinterpret_cast<const bf16x8*>(&As[(wr * 64 + m * 16 + lr) * 64 + ks * 32 + lk]);
#pragma unroll
      for (int n = 0; n < 4; ++n)
        bfr[n] = *reinterpret_cast<const bf16x8*>(&Bs[(wc * 64 + n * 16 + lr) * 64 + ks * 32 + lk]);
#pragma unroll
      for (int m = 0; m < 4; ++m)
#pragma unroll
        for (int n = 0; n < 4; ++n)
          acc[m][n] = __builtin_amdgcn_mfma_f32_16x16x32_bf16(af[m], bfr[n], acc[m][n], 0, 0, 0);
    }
  }
  // epilogue
#pragma unroll
  for (int m = 0; m < 4; ++m) {
    const int row_b = row0 + wr * 64 + m * 16 + (lane >> 4) * 4;
#pragma unroll
    for (int n = 0; n < 4; ++n) {
      const int col = col0 + wc * 64 + n * 16 + lr;
      const float bv = bias[col];
#pragma unroll
      for (int r = 0; r < 4; ++r) {
        const int row = row_b + r;
        float v = acc[m][n][r] + bv;
        if (RES) v += res[(size_t)row * N + col];
        if (GELU) v = 0.5f * v * (1.f + erff(v * 0.70710678118f));
        if (OUT_BF16) ((unsigned short*)Cout)[(size_t)row * N + col] = f2bf(v);
        else          ((float*)Cout)[(size_t)row * N + col] = v;
      }
    }
  }
}

// ---------------------------------------------------------------- flash attention
// Q,K,V bf16 [M_, E_] laid out per-head at col h*64. O bf16 same layout.
__global__ __launch_bounds__(256, 2)
void k_attn(const unsigned short* __restrict__ Q, const unsigned short* __restrict__ K,
            const unsigned short* __restrict__ V, unsigned short* __restrict__ O) {
  __shared__ unsigned short Ks[64 * 64];
  __shared__ unsigned short VT[64 * 64];
  __shared__ unsigned short Ps[4][16 * 64];
  const int t = threadIdx.x, lane = t & 63, w = t >> 6;
  const int qt = blockIdx.x, hh = blockIdx.y, bb = blockIdx.z;
  const int lr = lane & 15, lg = lane >> 4;
  const size_t base = (size_t)bb * N_ * E_ + hh * D_;
  const int q0 = qt * 64 + w * 16;

  bf16x8 qf[2];
#pragma unroll
  for (int ks = 0; ks < 2; ++ks)
    qf[ks] = *reinterpret_cast<const bf16x8*>(&Q[base + (size_t)(q0 + lr) * E_ + ks * 32 + lg * 8]);

  float mrow[4], lrow[4];
  f32x4 oacc[4];
#pragma unroll
  for (int r = 0; r < 4; ++r) { mrow[r] = -1e30f; lrow[r] = 0.f; }
#pragma unroll
  for (int d16 = 0; d16 < 4; ++d16) oacc[d16] = f32x4{0.f, 0.f, 0.f, 0.f};

  for (int kt = 0; kt < N_ / 64; ++kt) {
    __syncthreads();
#pragma unroll
    for (int c2 = 0; c2 < 2; ++c2) {
      int e = (t * 2 + c2) * 8;
      int r = e >> 6, c = e & 63;
      *reinterpret_cast<uint4*>(&Ks[r * 64 + c]) =
          *reinterpret_cast<const uint4*>(&K[base + (size_t)(kt * 64 + r) * E_ + c]);
      uint4 vv = *reinterpret_cast<const uint4*>(&V[base + (size_t)(kt * 64 + r) * E_ + c]);
      const unsigned short* pv = reinterpret_cast<const unsigned short*>(&vv);
#pragma unroll
      for (int j = 0; j < 8; ++j) VT[(c + j) * 64 + r] = pv[j];
    }
    __syncthreads();

    // S = Q K^T
    f32x4 sacc[4];
#pragma unroll
    for (int n16 = 0; n16 < 4; ++n16) sacc[n16] = f32x4{0.f, 0.f, 0.f, 0.f};
#pragma unroll
    for (int ks = 0; ks < 2; ++ks)
#pragma unroll
      for (int n16 = 0; n16 < 4; ++n16) {
        bf16x8 kf = *reinterpret_cast<const bf16x8*>(&Ks[(n16 * 16 + lr) * 64 + ks * 32 + lg * 8]);
        sacc[n16] = __builtin_amdgcn_mfma_f32_16x16x32_bf16(qf[ks], kf, sacc[n16], 0, 0, 0);
      }

    // online softmax (rows q0 + lg*4 + r ; cols n16*16 + lr)
    float p[4][4];
#pragma unroll
    for (int n16 = 0; n16 < 4; ++n16)
#pragma unroll
      for (int r = 0; r < 4; ++r) p[n16][r] = sacc[n16][r] * 0.03125f;
#pragma unroll
    for (int r = 0; r < 4; ++r) {
      float mx = fmaxf(fmaxf(p[0][r], p[1][r]), fmaxf(p[2][r], p[3][r]));
#pragma unroll
      for (int off = 1; off < 16; off <<= 1) mx = fmaxf(mx, __shfl_xor(mx, off));
      const float mnew = fmaxf(mrow[r], mx);
      const float alpha = expf(mrow[r] - mnew);
      mrow[r] = mnew;
      float ls = 0.f;
#pragma unroll
      for (int n16 = 0; n16 < 4; ++n16) { float pv = expf(p[n16][r] - mnew); p[n16][r] = pv; ls += pv; }
#pragma unroll
      for (int off = 1; off < 16; off <<= 1) ls += __shfl_xor(ls, off);
      lrow[r] = lrow[r] * alpha + ls;
#pragma unroll
      for (int d16 = 0; d16 < 4; ++d16) oacc[d16][r] *= alpha;
    }
    // P -> LDS (per-wave region)
#pragma unroll
    for (int n16 = 0; n16 < 4; ++n16)
#pragma unroll
      for (int r = 0; r < 4; ++r)
        Ps[w][(lg * 4 + r) * 64 + n16 * 16 + lr] = f2bf(p[n16][r]);

    // O += P V
#pragma unroll
    for (int ks = 0; ks < 2; ++ks) {
      bf16x8 pf = *reinterpret_cast<const bf16x8*>(&Ps[w][lr * 64 + ks * 32 + lg * 8]);
#pragma unroll
      for (int d16 = 0; d16 < 4; ++d16) {
        bf16x8 vf = *reinterpret_cast<const bf16x8*>(&VT[(d16 * 16 + lr) * 64 + ks * 32 + lg * 8]);
        oacc[d16] = __builtin_amdgcn_mfma_f32_16x16x32_bf16(pf, vf, oacc[d16], 0, 0, 0);
      }
    }
  }
  // write O
#pragma unroll
  for (int r = 0; r < 4; ++r) {
    const float inv = 1.f / lrow[r];
    const size_t rowoff = base + (size_t)(q0 + lg * 4 + r) * E_;
#pragma unroll
    for (int d16 = 0; d16 < 4; ++d16)
      O[rowoff + d16 * 16 + lr] = f2bf(oacc[d16][r] * inv);
  }
}

// ---------------------------------------------------------------- launch
extern "C" void kernel_launch(void* const* d_in, const int* in_sizes, int n_in,
                              void* d_out, int out_size, void* d_ws, size_t ws_size,
                              hipStream_t stream) {
  (void)in_sizes; (void)n_in; (void)out_size; (void)ws_size;
  const float* x     = (const float*)d_in[0];
  const float* Win   = (const float*)d_in[1];
  const float* bin   = (const float*)d_in[2];
  const float* gamma = (const float*)d_in[3];
  const float* beta  = (const float*)d_in[4];
  const float* Wq    = (const float*)d_in[5];
  const float* bq    = (const float*)d_in[6];
  const float* Wk    = (const float*)d_in[7];
  const float* bk    = (const float*)d_in[8];
  const float* Wv    = (const float*)d_in[9];
  const float* bv    = (const float*)d_in[10];
  const float* Wo    = (const float*)d_in[11];
  const float* bo    = (const float*)d_in[12];
  const float* W1    = (const float*)d_in[13];
  const float* b1    = (const float*)d_in[14];
  const float* W2    = (const float*)d_in[15];
  const float* b2    = (const float*)d_in[16];
  float* out = (float*)d_out;

  char* ws = (char*)d_ws;
  const size_t MB = 1024ull * 1024ull;
  float*          h   = (float*)         (ws + 0);        // 16 MB
  float*          h2  = (float*)         (ws + 16 * MB);  // 16 MB
  unsigned short* hL  = (unsigned short*)(ws + 32 * MB);  // 8 MB (also fLN)
  unsigned short* qb  = (unsigned short*)(ws + 40 * MB);  // 8 MB
  unsigned short* kb  = (unsigned short*)(ws + 48 * MB);  // 8 MB
  unsigned short* vb  = (unsigned short*)(ws + 56 * MB);  // 8 MB
  unsigned short* ao  = (unsigned short*)(ws + 64 * MB);  // 8 MB
  unsigned short* f1  = (unsigned short*)(ws + 40 * MB);  // 32 MB, reuses q/k/v/ao
  unsigned short* Wqt = (unsigned short*)(ws + 72 * MB);
  unsigned short* Wkt = (unsigned short*)(ws + 74 * MB);
  unsigned short* Wvt = (unsigned short*)(ws + 76 * MB);
  unsigned short* Wot = (unsigned short*)(ws + 78 * MB);
  unsigned short* W1t = (unsigned short*)(ws + 80 * MB);  // 8 MB
  unsigned short* W2t = (unsigned short*)(ws + 88 * MB);  // 8 MB  (total 96 MB)

  // weight convert+transpose
  k_transpose_bf16<<<dim3(E_ / 64, E_ / 64), 256, 0, stream>>>(Wq, Wqt, E_, E_);
  k_transpose_bf16<<<dim3(E_ / 64, E_ / 64), 256, 0, stream>>>(Wk, Wkt, E_, E_);
  k_transpose_bf16<<<dim3(E_ / 64, E_ / 64), 256, 0, stream>>>(Wv, Wvt, E_, E_);
  k_transpose_bf16<<<dim3(E_ / 64, E_ / 64), 256, 0, stream>>>(Wo, Wot, E_, E_);
  k_transpose_bf16<<<dim3(FF_ / 64, E_ / 64), 256, 0, stream>>>(W1, W1t, E_, FF_);
  k_transpose_bf16<<<dim3(E_ / 64, FF_ / 64), 256, 0, stream>>>(W2, W2t, FF_, E_);

  // h = x@Win + bin ; hL = LN(h)
  k_inproj_ln<<<M_, 256, 0, stream>>>(x, Win, bin, gamma, beta, h, hL);

  // q,k,v
  k_gemm<true, false, false><<<dim3(E_ / 128, M_ / 128), 256, 0, stream>>>(hL, Wqt, bq, nullptr, qb, M_, E_, E_);
  k_gemm<true, false, false><<<dim3(E_ / 128, M_ / 128), 256, 0, stream>>>(hL, Wkt, bk, nullptr, kb, M_, E_, E_);
  k_gemm<true, false, false><<<dim3(E_ / 128, M_ / 128), 256, 0, stream>>>(hL, Wvt, bv, nullptr, vb, M_, E_, E_);

  // attention
  k_attn<<<dim3(N_ / 64, H_, B_), 256, 0, stream>>>(qb, kb, vb, ao);

  // h2 = ao@Wo + bo + h
  k_gemm<false, false, true><<<dim3(E_ / 128, M_ / 128), 256, 0, stream>>>(ao, Wot, bo, h, h2, M_, E_, E_);

  // fLN = LN(h2)
  k_ln<<<M_, 256, 0, stream>>>(h2, gamma, beta, hL);

  // f1 = gelu(fLN@W1 + b1)
  k_gemm<true, true, false><<<dim3(FF_ / 128, M_ / 128), 256, 0, stream>>>(hL, W1t, b1, nullptr, f1, M_, FF_, E_);

  // out = f1@W2 + b2 + h2
  k_gemm<false, false, true><<<dim3(E_ / 128, M_ / 128), 256, 0, stream>>>(f1, W2t, b2, h2, out, M_, E_, FF_);
}

// Round 13
// 548.265 us; speedup vs baseline: 1.0371x; 1.0371x over previous
//
#include <hip/hip_runtime.h>
#include <hip/hip_bf16.h>
#include <stdint.h>
#include <math.h>

#define B_  2
#define N_  2048
#define E_  1024
#define H_  16
#define D_  64
#define FF_ 4096
#define M_  (B_ * N_)   // 4096 rows total

typedef __bf16 bf16x8 __attribute__((ext_vector_type(8)));
typedef float  f32x4  __attribute__((ext_vector_type(4)));

struct __align__(8) us4 { unsigned short v[4]; };

__device__ __forceinline__ unsigned short f2bf(float x) {
  union { float f; uint32_t u; } v; v.f = x;
  v.u += 0x7fffu + ((v.u >> 16) & 1u);   // RNE
  return (unsigned short)(v.u >> 16);
}

__device__ __forceinline__ void async16(void* lds, const void* g) {
  __builtin_amdgcn_global_load_lds(
      (const __attribute__((address_space(1))) uint32_t*)g,
      (__attribute__((address_space(3))) uint32_t*)lds, 16, 0, 0);
}

// ---------------------------------------------------------------- transpose+convert
// W [K,N] fp32  ->  Wt [N,K] bf16
__global__ __launch_bounds__(256)
void k_transpose_bf16(const float* __restrict__ W, unsigned short* __restrict__ Wt,
                      int K, int N) {
  __shared__ float tile[64][65];
  const int n0 = blockIdx.x * 64, k0 = blockIdx.y * 64;
  const int t = threadIdx.x;
  const int c = t & 63, r4 = t >> 6;
#pragma unroll
  for (int i = 0; i < 16; ++i) {
    int r = r4 + i * 4;
    tile[r][c] = W[(size_t)(k0 + r) * N + n0 + c];
  }
  __syncthreads();
#pragma unroll
  for (int i = 0; i < 16; ++i) {
    int r = r4 + i * 4;                       // output n-row
    Wt[(size_t)(n0 + r) * K + k0 + c] = f2bf(tile[c][r]);
  }
}

// ---------------------------------------------------------------- input proj + LN
__global__ __launch_bounds__(256)
void k_inproj_ln(const float* __restrict__ x, const float* __restrict__ Win,
                 const float* __restrict__ bin, const float* __restrict__ gamma,
                 const float* __restrict__ beta, float* __restrict__ h,
                 unsigned short* __restrict__ hL) {
  const int m = blockIdx.x, t = threadIdx.x;
  const float x0 = x[m * 2], x1 = x[m * 2 + 1];
  float hv[4], s = 0.f, s2 = 0.f;
#pragma unroll
  for (int i = 0; i < 4; ++i) {
    int c = t + i * 256;
    float v = x0 * Win[c] + x1 * Win[E_ + c] + bin[c];
    hv[i] = v; s += v; s2 += v * v;
  }
#pragma unroll
  for (int off = 1; off < 64; off <<= 1) { s += __shfl_xor(s, off); s2 += __shfl_xor(s2, off); }
  __shared__ float ws1[4], ws2[4];
  const int w = t >> 6, lane = t & 63;
  if (lane == 0) { ws1[w] = s; ws2[w] = s2; }
  __syncthreads();
  s  = ws1[0] + ws1[1] + ws1[2] + ws1[3];
  s2 = ws2[0] + ws2[1] + ws2[2] + ws2[3];
  const float mu = s * (1.f / E_);
  const float var = s2 * (1.f / E_) - mu * mu;
  const float rs = 1.f / sqrtf(var + 1e-5f);
#pragma unroll
  for (int i = 0; i < 4; ++i) {
    int c = t + i * 256;
    h [(size_t)m * E_ + c] = hv[i];
    hL[(size_t)m * E_ + c] = f2bf((hv[i] - mu) * rs * gamma[c] + beta[c]);
  }
}

// ---------------------------------------------------------------- LN (h2 -> bf16)
__global__ __launch_bounds__(256)
void k_ln(const float* __restrict__ h, const float* __restrict__ gamma,
          const float* __restrict__ beta, unsigned short* __restrict__ o) {
  const int m = blockIdx.x, t = threadIdx.x;
  const float4 v4 = *reinterpret_cast<const float4*>(&h[(size_t)m * E_ + t * 4]);
  float s = v4.x + v4.y + v4.z + v4.w;
  float s2 = v4.x * v4.x + v4.y * v4.y + v4.z * v4.z + v4.w * v4.w;
#pragma unroll
  for (int off = 1; off < 64; off <<= 1) { s += __shfl_xor(s, off); s2 += __shfl_xor(s2, off); }
  __shared__ float ws1[4], ws2[4];
  const int w = t >> 6, lane = t & 63;
  if (lane == 0) { ws1[w] = s; ws2[w] = s2; }
  __syncthreads();
  s  = ws1[0] + ws1[1] + ws1[2] + ws1[3];
  s2 = ws2[0] + ws2[1] + ws2[2] + ws2[3];
  const float mu = s * (1.f / E_);
  const float var = s2 * (1.f / E_) - mu * mu;
  const float rs = 1.f / sqrtf(var + 1e-5f);
  const float vv[4] = {v4.x, v4.y, v4.z, v4.w};
#pragma unroll
  for (int i = 0; i < 4; ++i) {
    int c = t * 4 + i;
    o[(size_t)m * E_ + c] = f2bf((vv[i] - mu) * rs * gamma[c] + beta[c]);
  }
}

// ---------------------------------------------------------------- GEMM
// C[M,N] = (A[M,K](bf16) * Bt[N,K](bf16)^T + bias) * scale  (+res) (+gelu)
// MODE: 0 = f32 out, 1 = bf16 out, 2 = bf16+gelu out, 3 = bf16 out in
//       attention-V^T layout [B][H][D][N] (packed 4 rows per write)
template <int MODE, bool RES>
__global__ __launch_bounds__(256, 2)
void k_gemm(const unsigned short* __restrict__ A, const unsigned short* __restrict__ Bt,
            const float* __restrict__ bias, const float* __restrict__ res,
            void* __restrict__ Cout, int M, int N, int K, float scale) {
  __shared__ unsigned short As[128 * 64];
  __shared__ unsigned short Bs[128 * 64];
  const int t = threadIdx.x, lane = t & 63, w = t >> 6;
  const int wr = w >> 1, wc = w & 1;

  // T1: bijective XCD-aware block swizzle (m204).
  const int nwg = gridDim.x * gridDim.y;
  const int orig = blockIdx.y * gridDim.x + blockIdx.x;
  const int q = nwg >> 3, r = nwg & 7;
  const int xcd = orig & 7, idx = orig >> 3;
  const int swz = (xcd < r ? xcd * (q + 1) : r * (q + 1) + (xcd - r) * q) + idx;
  const int bx = swz % gridDim.x, by = swz / gridDim.x;

  const int row0 = by * 128, col0 = bx * 128;
  const int lr = lane & 15, lg = lane >> 4, lk = lg * 8;

  f32x4 acc[4][4];
#pragma unroll
  for (int m = 0; m < 4; ++m)
#pragma unroll
    for (int n = 0; n < 4; ++n) acc[m][n] = f32x4{0.f, 0.f, 0.f, 0.f};

  for (int k0 = 0; k0 < K; k0 += 64) {
    __syncthreads();
#pragma unroll
    for (int it = 0; it < 4; ++it) {
      int e = (it * 256 + t) * 8;
      int r2 = e >> 6, c = e & 63;
      async16(&As[(it * 256 + w * 64) * 8], &A [(size_t)(row0 + r2) * K + k0 + c]);
      async16(&Bs[(it * 256 + w * 64) * 8], &Bt[(size_t)(col0 + r2) * K + k0 + c]);
    }
    __syncthreads();
#pragma unroll
    for (int ks = 0; ks < 2; ++ks) {
      bf16x8 af[4], bfr[4];
#pragma unroll
      for (int m = 0; m < 4; ++m)
        af[m] = *reinterpret_cast<const bf16x8*>(&As[(wr * 64 + m * 16 + lr) * 64 + ks * 32 + lk]);
#pragma unroll
      for (int n = 0; n < 4; ++n)
        bfr[n] = *reinterpret_cast<const bf16x8*>(&Bs[(wc * 64 + n * 16 + lr) * 64 + ks * 32 + lk]);
#pragma unroll
      for (int m = 0; m < 4; ++m)
#pragma unroll
        for (int n = 0; n < 4; ++n)
          acc[m][n] = __builtin_amdgcn_mfma_f32_16x16x32_bf16(af[m], bfr[n], acc[m][n], 0, 0, 0);
    }
  }
  // epilogue
#pragma unroll
  for (int m = 0; m < 4; ++m) {
    const int row_b = row0 + wr * 64 + m * 16 + lg * 4;
#pragma unroll
    for (int n = 0; n < 4; ++n) {
      const int col = col0 + wc * 64 + n * 16 + lr;
      const float bv = bias[col];
      if (MODE == 3) {
        us4 pk;
#pragma unroll
        for (int rr = 0; rr < 4; ++rr) pk.v[rr] = f2bf((acc[m][n][rr] + bv) * scale);
        const int hh = col >> 6, dd = col & 63;
        const int bb = row_b >> 11, ns = row_b & (N_ - 1);
        *reinterpret_cast<us4*>(
            &((unsigned short*)Cout)[((size_t)(bb * H_ + hh) * D_ + dd) * N_ + ns]) = pk;
      } else {
#pragma unroll
        for (int rr = 0; rr < 4; ++rr) {
          const int row = row_b + rr;
          float v = (acc[m][n][rr] + bv) * scale;
          if (RES) v += res[(size_t)row * N + col];
          if (MODE == 2) v = 0.5f * v * (1.f + erff(v * 0.70710678118f));
          if (MODE == 0) ((float*)Cout)[(size_t)row * N + col] = v;
          else           ((unsigned short*)Cout)[(size_t)row * N + col] = f2bf(v);
        }
      }
    }
  }
}

// ---------------------------------------------------------------- flash attention
// ROUND-0 NUMERICS (known-good: absmax 0.029): KBLK=64, max-tracked expf
// softmax, scale applied post-MFMA, no LDS swizzles. Only change vs Round 0:
// V arrives pre-transposed as VTg [B][H][D][N] (from the V-GEMM epilogue),
// staged by direct uint4 copies — the in-kernel scalar transpose is gone.
__global__ __launch_bounds__(256, 2)
void k_attn(const unsigned short* __restrict__ Q, const unsigned short* __restrict__ K,
            const unsigned short* __restrict__ VTg, unsigned short* __restrict__ O) {
  __shared__ unsigned short Ks[64 * 64];        // [kseq][d]
  __shared__ unsigned short VT[64 * 64];        // [d][kseq]
  __shared__ unsigned short Ps[4][16 * 64];     // per-wave [q][kseq]
  const int t = threadIdx.x, lane = t & 63, w = t >> 6;
  const int qt = blockIdx.x, hh = blockIdx.y, bb = blockIdx.z;
  const int lr = lane & 15, lg = lane >> 4;
  const size_t base = (size_t)bb * N_ * E_ + hh * D_;
  const size_t vtbase = (size_t)(bb * H_ + hh) * D_ * N_;
  const int q0 = qt * 64 + w * 16;

  bf16x8 qf[2];
#pragma unroll
  for (int ks = 0; ks < 2; ++ks)
    qf[ks] = *reinterpret_cast<const bf16x8*>(&Q[base + (size_t)(q0 + lr) * E_ + ks * 32 + lg * 8]);

  float mrow[4], lrow[4];
  f32x4 oacc[4];
#pragma unroll
  for (int r = 0; r < 4; ++r) { mrow[r] = -1e30f; lrow[r] = 0.f; }
#pragma unroll
  for (int d16 = 0; d16 < 4; ++d16) oacc[d16] = f32x4{0.f, 0.f, 0.f, 0.f};

  for (int kt = 0; kt < N_ / 64; ++kt) {
    __syncthreads();
#pragma unroll
    for (int c2 = 0; c2 < 2; ++c2) {
      const int s = t * 2 + c2;
      const int r = s >> 3, c = (s & 7) * 8;
      *reinterpret_cast<uint4*>(&Ks[r * 64 + c]) =
          *reinterpret_cast<const uint4*>(&K[base + (size_t)(kt * 64 + r) * E_ + c]);
      *reinterpret_cast<uint4*>(&VT[r * 64 + c]) =
          *reinterpret_cast<const uint4*>(&VTg[vtbase + (size_t)r * N_ + kt * 64 + c]);
    }
    __syncthreads();

    // S = Q K^T
    f32x4 sacc[4];
#pragma unroll
    for (int n16 = 0; n16 < 4; ++n16) sacc[n16] = f32x4{0.f, 0.f, 0.f, 0.f};
#pragma unroll
    for (int ks = 0; ks < 2; ++ks)
#pragma unroll
      for (int n16 = 0; n16 < 4; ++n16) {
        bf16x8 kf = *reinterpret_cast<const bf16x8*>(&Ks[(n16 * 16 + lr) * 64 + ks * 32 + lg * 8]);
        sacc[n16] = __builtin_amdgcn_mfma_f32_16x16x32_bf16(qf[ks], kf, sacc[n16], 0, 0, 0);
      }

    // online softmax (rows q0 + lg*4 + r ; cols n16*16 + lr)
    float p[4][4];
#pragma unroll
    for (int n16 = 0; n16 < 4; ++n16)
#pragma unroll
      for (int r = 0; r < 4; ++r) p[n16][r] = sacc[n16][r] * 0.03125f;
#pragma unroll
    for (int r = 0; r < 4; ++r) {
      float mx = fmaxf(fmaxf(p[0][r], p[1][r]), fmaxf(p[2][r], p[3][r]));
#pragma unroll
      for (int off = 1; off < 16; off <<= 1) mx = fmaxf(mx, __shfl_xor(mx, off));
      const float mnew = fmaxf(mrow[r], mx);
      const float alpha = expf(mrow[r] - mnew);
      mrow[r] = mnew;
      float ls = 0.f;
#pragma unroll
      for (int n16 = 0; n16 < 4; ++n16) { float pv = expf(p[n16][r] - mnew); p[n16][r] = pv; ls += pv; }
#pragma unroll
      for (int off = 1; off < 16; off <<= 1) ls += __shfl_xor(ls, off);
      lrow[r] = lrow[r] * alpha + ls;
#pragma unroll
      for (int d16 = 0; d16 < 4; ++d16) oacc[d16][r] *= alpha;
    }
    // P -> LDS (per-wave region)
#pragma unroll
    for (int n16 = 0; n16 < 4; ++n16)
#pragma unroll
      for (int r = 0; r < 4; ++r)
        Ps[w][(lg * 4 + r) * 64 + n16 * 16 + lr] = f2bf(p[n16][r]);

    // O += P V
#pragma unroll
    for (int ks = 0; ks < 2; ++ks) {
      bf16x8 pf = *reinterpret_cast<const bf16x8*>(&Ps[w][lr * 64 + ks * 32 + lg * 8]);
#pragma unroll
      for (int d16 = 0; d16 < 4; ++d16) {
        bf16x8 vf = *reinterpret_cast<const bf16x8*>(&VT[(d16 * 16 + lr) * 64 + ks * 32 + lg * 8]);
        oacc[d16] = __builtin_amdgcn_mfma_f32_16x16x32_bf16(pf, vf, oacc[d16], 0, 0, 0);
      }
    }
  }
  // write O
#pragma unroll
  for (int r = 0; r < 4; ++r) {
    const float inv = 1.f / lrow[r];
    const size_t rowoff = base + (size_t)(q0 + lg * 4 + r) * E_;
#pragma unroll
    for (int d16 = 0; d16 < 4; ++d16)
      O[rowoff + d16 * 16 + lr] = f2bf(oacc[d16][r] * inv);
  }
}

// ---------------------------------------------------------------- launch
extern "C" void kernel_launch(void* const* d_in, const int* in_sizes, int n_in,
                              void* d_out, int out_size, void* d_ws, size_t ws_size,
                              hipStream_t stream) {
  (void)in_sizes; (void)n_in; (void)out_size; (void)ws_size;
  const float* x     = (const float*)d_in[0];
  const float* Win   = (const float*)d_in[1];
  const float* bin   = (const float*)d_in[2];
  const float* gamma = (const float*)d_in[3];
  const float* beta  = (const float*)d_in[4];
  const float* Wq    = (const float*)d_in[5];
  const float* bq    = (const float*)d_in[6];
  const float* Wk    = (const float*)d_in[7];
  const float* bk    = (const float*)d_in[8];
  const float* Wv    = (const float*)d_in[9];
  const float* bv    = (const float*)d_in[10];
  const float* Wo    = (const float*)d_in[11];
  const float* bo    = (const float*)d_in[12];
  const float* W1    = (const float*)d_in[13];
  const float* b1    = (const float*)d_in[14];
  const float* W2    = (const float*)d_in[15];
  const float* b2    = (const float*)d_in[16];
  float* out = (float*)d_out;

  char* ws = (char*)d_ws;
  const size_t MB = 1024ull * 1024ull;
  float*          h   = (float*)         (ws + 0);        // 16 MB
  float*          h2  = (float*)         (ws + 16 * MB);  // 16 MB
  unsigned short* hL  = (unsigned short*)(ws + 32 * MB);  // 8 MB (also fLN)
  unsigned short* qb  = (unsigned short*)(ws + 40 * MB);  // 8 MB
  unsigned short* kb  = (unsigned short*)(ws + 48 * MB);  // 8 MB
  unsigned short* vt  = (unsigned short*)(ws + 56 * MB);  // 8 MB  V^T [B][H][D][N]
  unsigned short* ao  = (unsigned short*)(ws + 64 * MB);  // 8 MB
  unsigned short* f1  = (unsigned short*)(ws + 40 * MB);  // 32 MB, reuses qb/kb/vt/ao
  unsigned short* Wqt = (unsigned short*)(ws + 72 * MB);
  unsigned short* Wkt = (unsigned short*)(ws + 74 * MB);
  unsigned short* Wvt = (unsigned short*)(ws + 76 * MB);
  unsigned short* Wot = (unsigned short*)(ws + 78 * MB);
  unsigned short* W1t = (unsigned short*)(ws + 80 * MB);  // 8 MB
  unsigned short* W2t = (unsigned short*)(ws + 88 * MB);  // 8 MB  (total 96 MB)

  // weight convert+transpose
  k_transpose_bf16<<<dim3(E_ / 64, E_ / 64), 256, 0, stream>>>(Wq, Wqt, E_, E_);
  k_transpose_bf16<<<dim3(E_ / 64, E_ / 64), 256, 0, stream>>>(Wk, Wkt, E_, E_);
  k_transpose_bf16<<<dim3(E_ / 64, E_ / 64), 256, 0, stream>>>(Wv, Wvt, E_, E_);
  k_transpose_bf16<<<dim3(E_ / 64, E_ / 64), 256, 0, stream>>>(Wo, Wot, E_, E_);
  k_transpose_bf16<<<dim3(FF_ / 64, E_ / 64), 256, 0, stream>>>(W1, W1t, E_, FF_);
  k_transpose_bf16<<<dim3(E_ / 64, FF_ / 64), 256, 0, stream>>>(W2, W2t, FF_, E_);

  // h = x@Win + bin ; hL = LN(h)
  k_inproj_ln<<<M_, 256, 0, stream>>>(x, Win, bin, gamma, beta, h, hL);

  // q, k, v (v written as V^T)
  k_gemm<1, false><<<dim3(E_ / 128, M_ / 128), 256, 0, stream>>>(hL, Wqt, bq, nullptr, qb, M_, E_, E_, 1.f);
  k_gemm<1, false><<<dim3(E_ / 128, M_ / 128), 256, 0, stream>>>(hL, Wkt, bk, nullptr, kb, M_, E_, E_, 1.f);
  k_gemm<3, false><<<dim3(E_ / 128, M_ / 128), 256, 0, stream>>>(hL, Wvt, bv, nullptr, vt, M_, E_, E_, 1.f);

  // attention
  k_attn<<<dim3(N_ / 64, H_, B_), 256, 0, stream>>>(qb, kb, vt, ao);

  // h2 = ao@Wo + bo + h
  k_gemm<0, true><<<dim3(E_ / 128, M_ / 128), 256, 0, stream>>>(ao, Wot, bo, h, h2, M_, E_, E_, 1.f);

  // fLN = LN(h2)
  k_ln<<<M_, 256, 0, stream>>>(h2, gamma, beta, hL);

  // f1 = gelu(fLN@W1 + b1)
  k_gemm<2, false><<<dim3(FF_ / 128, M_ / 128), 256, 0, stream>>>(hL, W1t, b1, nullptr, f1, M_, FF_, E_, 1.f);

  // out = f1@W2 + b2 + h2
  k_gemm<0, true><<<dim3(E_ / 128, M_ / 128), 256, 0, stream>>>(f1, W2t, b2, h2, out, M_, E_, FF_, 1.f);
}